// Round 14
// baseline (249.522 us; speedup 1.0000x reference)
//
#include <hip/hip_runtime.h>

// GridSamplePScan: out[b,t,c] = sum_{k<=t} bilinear(images[b,k,c], base_grid + (cum[t]-cum[k]))
// B=2, L=24, C=16, H=W=64 fp32. align_corners=False, zero pad, x wrapped into [-1,1).
//
// R14: fixed-window band staging (evolves R13's measured 84us).
//   - FIXED 12-row window [wlo,wlo+11], wlo=clamp(y-5): no band-reduce, no bandW barrier
//     traffic; k-invariant staging addresses. |y-shift|>~5px (sigma=1.5) -> per-lane
//     global-gather fallback (~1-2% of waves, exact same arithmetic).
//   - Staging writes LINEAR: slot=(c,rowgroup); lane byte-offset = lane*16 within each
//     ds_write_b128 -> conflict-free (R11/R13's 6M conflicts were the c-strided writes).
//   - Sampling reads PAIRED: need lds[r][p],lds[r][p+1] (adjacent) -> 2 adjacent b32
//     (ds_read2_b32 merge) x 2 rows x 16ch = 32 read-instrs/wave/k (was 64). Edge cases
//     (x-clamp at 0/63) handled by remapped weights wA0/wA1 via e0/e1 selects.
//   - Reg-staged prefetch: plane k+1's 8 float4 loads issued BEFORE sampling k; written
//     to LDS after barrier (T14). 2 barriers/k-step, single 48KB buffer, 2 blocks/CU.
//   - bid&7 = y>>3: XCD L2 y-banding (measured -23MB FETCH in R6).
//   - cum chain: two-pass ascending, bit-matches jnp.cumsum (all passing rounds).

#define BB 2
#define LL 24
#define CC 16
#define HH 64
#define WW 64
#define HW (HH * WW)
#define NW 6                 // waves per block
#define WROWS 12             // fixed window rows
#define CHS (WROWS * WW)     // channel slab stride in floats = 768 (3072 B)

__global__ __launch_bounds__(NW * 64, 3) void gsps_fixw(
    const float* __restrict__ flows,   // [B,L,2,H,W]
    const float* __restrict__ images,  // [B,L,C,H,W]
    float* __restrict__ out)           // [B,L,C,H,W]
{
    __shared__ float lds[CC * CHS];    // 49152 B, [c][row][x] channels-first

    // bid = ((b*4 + q)*8 + y_lo)*8 + y_hi  -> bid&7 = y>>3 (XCD y-banding)
    const int bid = blockIdx.x;
    const int y_hi = bid & 7;
    int u = bid >> 3;
    const int y_lo = u & 7; u >>= 3;
    const int q = u & 3;
    const int b = u >> 2;
    const int y = (y_hi << 3) | y_lo;
    const int lane = threadIdx.x & 63;
    const int w = threadIdx.x >> 6;          // wave id 0..5
    const int t = q + 4 * w;                 // this wave's output frame
    const int kmax = q + 20;                 // largest t in block (block-uniform)
    const int lg = lane >> 4;                // row-subgroup 0..3
    const int li = lane & 15;                // 16 lanes x 16B = 256B row

    const int wlo = min(max(y - 5, 0), HH - WROWS);   // fixed window start

    const float gx = -0.984375f + (float)lane * 0.03125f;
    const float gy = -0.984375f + (float)y * 0.03125f;
    const int pix = y * WW + lane;
    const float* fb = flows + (size_t)b * LL * 2 * HW + pix;

    // pass 1: cum[t] ascending (bit-matches jnp.cumsum)
    float ctx = 0.0f, cty = 0.0f;
    for (int i = 0; i <= t; ++i) {
        ctx += fb[(size_t)(2 * i) * HW];
        cty += fb[(size_t)(2 * i + 1) * HW];
    }

    float acc[CC];
#pragma unroll
    for (int c = 0; c < CC; ++c) acc[c] = 0.0f;

    float cx = 0.0f, cy = 0.0f;
    float fkx = fb[0], fky = fb[HW];

    // ---- prologue: stage plane k=0 (8 slots per wave: slot = w + 6s, s=0..7) ----
    {
        const float* img0 = images + (size_t)(b * LL) * (CC * HW);
        float4 st[8];
#pragma unroll
        for (int s = 0; s < 8; ++s) {
            const int slot = w + s * NW;     // [0,48)
            const int c = slot & 15, rg = slot >> 4;
            st[s] = *(const float4*)(img0 + (size_t)c * HW + (wlo + rg * 4 + lg) * WW + li * 4);
        }
#pragma unroll
        for (int s = 0; s < 8; ++s) {
            const int slot = w + s * NW;
            const int c = slot & 15, rg = slot >> 4;
            // byte offset within slab = (rg*4+lg)*256 + li*16 = rg*1024 + lane*16: LINEAR
            *(float4*)&lds[c * CHS + (rg * 4 + lg) * WW + li * 4] = st[s];
        }
    }
    __syncthreads();

    for (int k = 0; k <= kmax; ++k) {
        cx += fkx; cy += fky;                // cum[k]
        if (k < kmax) {                      // prefetch flow[k+1]
            fkx = fb[(size_t)(2 * (k + 1)) * HW];
            fky = fb[(size_t)(2 * (k + 1) + 1) * HW];
        }

        // ---- issue plane-(k+1) staging loads FIRST (latency hides under sampling) ----
        float4 st[8];
        if (k < kmax) {
            const float* imgn = images + (size_t)(b * LL + k + 1) * (CC * HW);
#pragma unroll
            for (int s = 0; s < 8; ++s) {
                const int slot = w + s * NW;
                const int c = slot & 15, rg = slot >> 4;
                st[s] = *(const float4*)(imgn + (size_t)c * HW + (wlo + rg * 4 + lg) * WW + li * 4);
            }
        }

        // ---- coordinates (exact wrap semantics, identical to all passing rounds) ----
        const bool act = (t >= k);
        if (act) {
            const float relx = ctx - cx, rely = cty - cy;
            const float v = (gx + relx) + 1.0f;
            float r = v - 2.0f * truncf(v * 0.5f);   // == fmodf(v,2), exact for |v|<4
            r = (r < 0.0f) ? (r + 2.0f) : r;
            const float gxv = r - 1.0f;
            const float gyv = gy + rely;

            const float ix = (gxv + 1.0f) * 32.0f - 0.5f;
            const float iy = (gyv + 1.0f) * 32.0f - 0.5f;

            const float x0f = floorf(ix), y0f = floorf(iy);
            const float x1f = x0f + 1.0f, y1f = y0f + 1.0f;
            const float wx1 = ix - x0f, wx0 = 1.0f - wx1;
            const float wy1 = iy - y0f, wy0 = 1.0f - wy1;

            const bool vx0 = (x0f >= 0.0f) && (x0f <= 63.0f);
            const bool vx1 = (x1f >= 0.0f) && (x1f <= 63.0f);
            const bool vy0 = (y0f >= 0.0f) && (y0f <= 63.0f);
            const bool vy1 = (y1f >= 0.0f) && (y1f <= 63.0f);

            const int x0c = min(max((int)x0f, 0), WW - 1);
            const int x1c = min(max((int)x1f, 0), WW - 1);
            const int y0c = min(max((int)y0f, 0), HH - 1);
            const int y1c = min(max((int)y1f, 0), HH - 1);

            const float w00 = (vx0 && vy0) ? (wx0 * wy0) : 0.0f;
            const float w10 = (vx1 && vy0) ? (wx1 * wy0) : 0.0f;
            const float w01 = (vx0 && vy1) ? (wx0 * wy1) : 0.0f;
            const float w11 = (vx1 && vy1) ? (wx1 * wy1) : 0.0f;

            const bool flb = (y0c < wlo) || (y1c > wlo + (WROWS - 1));

            if (!flb) {
                // paired-column weights: columns {p, p+1}, p in [0,62]
                const int p = min(max((int)x0f, 0), WW - 2);
                const bool e0 = (x0c == p);          // x0c is column p (else p+1)
                const bool e1 = (x1c == p);          // x1c is column p (else p+1)
                const float wA0 = (e0 ? w00 : 0.0f) + (e1 ? w10 : 0.0f);
                const float wA1 = (e0 ? 0.0f : w00) + (e1 ? 0.0f : w10);
                const float wB0 = (e0 ? w01 : 0.0f) + (e1 ? w11 : 0.0f);
                const float wB1 = (e0 ? 0.0f : w01) + (e1 ? 0.0f : w11);
                const int baseA = (y0c - wlo) * WW + p;
                const int baseB = (y1c - wlo) * WW + p;
#pragma unroll
                for (int c = 0; c < CC; ++c) {
                    const float vA0 = lds[c * CHS + baseA];
                    const float vA1 = lds[c * CHS + baseA + 1];   // adjacent -> ds_read2_b32
                    const float vB0 = lds[c * CHS + baseB];
                    const float vB1 = lds[c * CHS + baseB + 1];
                    acc[c] += vA0 * wA0 + vA1 * wA1 + vB0 * wB0 + vB1 * wB1;
                }
            } else {
                // rare (|shift|>5px) per-lane fallback: identical arithmetic from global
                const float* imgk = images + (size_t)(b * LL + k) * (CC * HW);
                const int g00 = y0c * WW + x0c, g10 = y0c * WW + x1c;
                const int g01 = y1c * WW + x0c, g11 = y1c * WW + x1c;
#pragma unroll
                for (int c = 0; c < CC; ++c) {
                    const float* pc = imgk + (size_t)c * HW;
                    acc[c] += pc[g00] * w00 + pc[g10] * w10 + pc[g01] * w01 + pc[g11] * w11;
                }
            }
        }

        __syncthreads();   // all reads of band k complete
        if (k < kmax) {
#pragma unroll
            for (int s = 0; s < 8; ++s) {
                const int slot = w + s * NW;
                const int c = slot & 15, rg = slot >> 4;
                *(float4*)&lds[c * CHS + (rg * 4 + lg) * WW + li * 4] = st[s];
            }
        }
        __syncthreads();   // band k+1 staged
    }

    float* o = out + ((size_t)(b * LL + t) * CC) * HW + pix;
#pragma unroll
    for (int c = 0; c < CC; ++c) o[(size_t)c * HW] = acc[c];
}

extern "C" void kernel_launch(void* const* d_in, const int* in_sizes, int n_in,
                              void* d_out, int out_size, void* d_ws, size_t ws_size,
                              hipStream_t stream) {
    const float* flows  = (const float*)d_in[0];   // [B,L,2,H,W]
    const float* images = (const float*)d_in[1];   // [B,L,C,H,W]
    float* out = (float*)d_out;                    // [B,L,C,H,W]

    const int nblk = BB * 4 * HH;                  // 512 blocks x 384 threads = 2/CU
    gsps_fixw<<<nblk, NW * 64, 0, stream>>>(flows, images, out);
}